// Round 7
// baseline (234.603 us; speedup 1.0000x reference)
//
#include <hip/hip_runtime.h>
#include <hip/hip_cooperative_groups.h>
namespace cg = cooperative_groups;

#define SKV  1024
#define NSQ  512
#define HIN  256
#define HA   128
#define NQ   1024            // total q rows (B*SQ)
#define NR   2048            // total kv rows (B*S)

// proj stores E = exp2(KSC*p) = e^{2p};  tanh(pk+pq) = 1 - 2/(Ek*Eq+1)
// score' = -2*sum_a wv_a/(Ek*Eq+1)   (W0+bv constants cancel in softmax)
#define KSC 2.8853900817779268f      // 2*log2(e)

typedef float v2f __attribute__((ext_vector_type(2)));
__device__ __forceinline__ v2f pkfma(v2f a, v2f b, v2f c) {
    return __builtin_elementwise_fma(a, b, c);
}

// one block per CU; 16 waves; phases separated by grid.sync()
__global__ __launch_bounds__(1024, 4) void fused_kernel(
    const float* __restrict__ kv,  const float* __restrict__ qy,
    const float* __restrict__ Wkv, const float* __restrict__ bkv,
    const float* __restrict__ Wq,  const float* __restrict__ bq,
    const float* __restrict__ wv,
    float* __restrict__ ekT,       // [HA][NR]
    float* __restrict__ eq,        // [NQ][HA]
    float* __restrict__ ew,        // [NQ][SKV]
    float* __restrict__ ewT,       // [NQ/8][SKV][8]
    float* __restrict__ Dp,        // [2][NQ]
    float* __restrict__ P2,        // [2][NQ*HIN]
    float* __restrict__ out)       // [262144 out0][1048576 weights]
{
    cg::grid_group grid = cg::this_grid();
    __shared__ float smem[8 * 16 * 128];   // 64 KB, phase-dependent views
    const int t    = threadIdx.x;
    const int blk  = blockIdx.x;           // 0..255
    const int lane = t & 63;
    const int w    = t >> 6;               // wave 0..15

    // ================= phase A: projections -> ekT, eq =================
    // wave-pairs g=0/1: 8 kv rows (h-halves); g=2/3: 4 q rows (h-halves).
    {
        const int a = t & 127;
        const int g = __builtin_amdgcn_readfirstlane(t >> 7);  // 0..7, wave-uniform
        if (g < 4) {
            const int role = g >> 1;       // 0 = kv, 1 = q
            const int gh   = g & 1;        // h-half
            const float* __restrict__ W = (role ? Wq : Wkv) + (size_t)gh * 128 * HA;
            const float* __restrict__ src = (role ? (qy + (size_t)blk * 4 * HIN)
                                                  : (kv + (size_t)blk * 8 * HIN)) + gh * 128;
            if (role == 0) {
                float ac[8] = {0,0,0,0,0,0,0,0};
                #pragma unroll 4
                for (int h = 0; h < 128; ++h) {
                    const float wl = W[(size_t)h * HA + a];    // coalesced
                    #pragma unroll
                    for (int r = 0; r < 8; ++r)
                        ac[r] = fmaf(src[(size_t)r * HIN + h], wl, ac[r]);  // uniform
                }
                #pragma unroll
                for (int r = 0; r < 8; ++r) smem[(gh * 12 + r) * 128 + a] = ac[r];
            } else {
                float ac[4] = {0,0,0,0};
                #pragma unroll 4
                for (int h = 0; h < 128; ++h) {
                    const float wl = W[(size_t)h * HA + a];
                    #pragma unroll
                    for (int r = 0; r < 4; ++r)
                        ac[r] = fmaf(src[(size_t)r * HIN + h], wl, ac[r]);
                }
                #pragma unroll
                for (int r = 0; r < 4; ++r) smem[(gh * 12 + 8 + r) * 128 + a] = ac[r];
            }
        }
        __syncthreads();
        #pragma unroll
        for (int id = t; id < 1536; id += 1024) {   // 12 rows x 128 ch (FIX: was if(t<1536))
            const int r = id >> 7, a2 = id & 127;
            const float v  = smem[r * 128 + a2] + smem[(12 + r) * 128 + a2];
            const bool isq = r >= 8;
            const float bb = (isq ? bq : bkv)[a2];
            const float o  = __builtin_amdgcn_exp2f((v + bb) * KSC);
            if (!isq) ekT[(size_t)a2 * NR + blk * 8 + r] = o;
            else      eq[((size_t)blk * 4 + (r - 8)) * HA + a2] = o;
        }
    }
    grid.sync();

    // ================= phase B: scores + exp -> ew, ewT, Dp =================
    // block = (oct, s-half); thread-half = q-half; 4 q x 128 a per thread
    {
        const int oct = blk >> 1, sh = blk & 1;
        const int q0  = oct * 8;
        const int b   = q0 >> 9;
        const int qh  = __builtin_amdgcn_readfirstlane(t >> 9);  // 0/1
        const int s   = sh * 512 + (t & 511);
        const int srow = b * SKV + s;

        v2f acc[4];
        #pragma unroll
        for (int j = 0; j < 4; ++j) acc[j] = (v2f){0.f, 0.f};
        const v2f one = {1.f, 1.f};

        #pragma unroll 2
        for (int a4 = 0; a4 < 32; ++a4) {
            const float E0 = ekT[(size_t)(a4 * 4 + 0) * NR + srow];  // coalesced
            const float E1 = ekT[(size_t)(a4 * 4 + 1) * NR + srow];
            const float E2 = ekT[(size_t)(a4 * 4 + 2) * NR + srow];
            const float E3 = ekT[(size_t)(a4 * 4 + 3) * NR + srow];
            const float4 w4 = *(const float4*)(wv + a4 * 4);         // uniform
            const v2f E01 = {E0, E1}, E23 = {E2, E3};
            const v2f w01 = {w4.x, w4.y}, w23 = {w4.z, w4.w};
            #pragma unroll
            for (int j = 0; j < 4; ++j) {
                const float4 qv = *(const float4*)(eq + ((size_t)q0 + qh * 4 + j) * HA + a4 * 4);
                const v2f A = pkfma(E01, (v2f){qv.x, qv.y}, one);
                const v2f B = pkfma(E23, (v2f){qv.z, qv.w}, one);
                const v2f m = A * B;
                const float r = __builtin_amdgcn_rcpf(m.x * m.y);
                const v2f ts = (v2f){m.y, m.x} * (v2f){r, r};        // (1/m.x, 1/m.y)
                acc[j] = pkfma(w01, ts * B, acc[j]);
                acc[j] = pkfma(w23, ts * A, acc[j]);
            }
        }
        float ev[4];
        #pragma unroll
        for (int j = 0; j < 4; ++j) {
            ev[j] = __builtin_amdgcn_exp2f(-KSC * (acc[j].x + acc[j].y));
            ew[((size_t)q0 + qh * 4 + j) * SKV + s] = ev[j];         // coalesced
        }
        *(float4*)(ewT + ((size_t)oct * SKV + s) * 8 + qh * 4) =
            make_float4(ev[0], ev[1], ev[2], ev[3]);

        float* dred = smem;                // [16][4]
        #pragma unroll
        for (int j = 0; j < 4; ++j) {
            float ssum = ev[j];
            #pragma unroll
            for (int o = 32; o > 0; o >>= 1) ssum += __shfl_down(ssum, o);
            if (lane == 0) dred[w * 4 + j] = ssum;
        }
        __syncthreads();
        if ((t & 511) < 4) {
            const int j = t & 3;
            const int base = qh * 32;      // waves 0..7 | 8..15
            float d = 0.f;
            #pragma unroll
            for (int k = 0; k < 8; ++k) d += dred[base + k * 4 + j];
            Dp[(size_t)sh * NQ + q0 + qh * 4 + j] = d;
        }
    }
    grid.sync();

    // ============ phase C: weights out + output-GEMM partials ============
    // block = (q16-group gi, h-half hh, s-half sh)
    {
        const int gi  = blk >> 2;
        const int hh  = (blk >> 1) & 1;
        const int sh  = blk & 1;
        const int q0g = gi * 16;
        const int b   = q0g >> 9;
        const int o0  = gi * 2;

        if (hh == 0) {                     // normalized attention weights
            const int jh = __builtin_amdgcn_readfirstlane(t >> 9);
            const int s  = sh * 512 + (t & 511);
            float* __restrict__ outw = out + (size_t)NQ * HIN;
            #pragma unroll
            for (int jj = 0; jj < 8; ++jj) {
                const int qq = q0g + jh * 8 + jj;
                const float D = Dp[qq] + Dp[NQ + qq];
                outw[(size_t)qq * SKV + s] =
                    ew[(size_t)qq * SKV + s] * __builtin_amdgcn_rcpf(D);
            }
        }

        // GEMM: wave <-> 32-s chunk; lane <-> h-pair in half
        const int sbase = sh * 512 + w * 32;
        const float* __restrict__ kvp =
            kv + ((size_t)(b * SKV + sbase)) * HIN + hh * 128 + lane * 2;
        const float* __restrict__ wA = ewT + ((size_t)o0 * SKV + sbase) * 8;
        const float* __restrict__ wB = ewT + ((size_t)(o0 + 1) * SKV + sbase) * 8;

        v2f acc[16];
        #pragma unroll
        for (int j = 0; j < 16; ++j) acc[j] = (v2f){0.f, 0.f};
        #pragma unroll 2
        for (int i = 0; i < 32; ++i) {
            const v2f v = *(const v2f*)(kvp + (size_t)i * HIN);      // coalesced 512B
            const float4 a0 = *(const float4*)(wA + i * 8);          // broadcast
            const float4 a1 = *(const float4*)(wA + i * 8 + 4);
            const float4 b0 = *(const float4*)(wB + i * 8);
            const float4 b1 = *(const float4*)(wB + i * 8 + 4);
            const float wq[16] = {a0.x, a0.y, a0.z, a0.w, a1.x, a1.y, a1.z, a1.w,
                                  b0.x, b0.y, b0.z, b0.w, b1.x, b1.y, b1.z, b1.w};
            #pragma unroll
            for (int j = 0; j < 16; ++j)
                acc[j] = pkfma(v, (v2f){wq[j], wq[j]}, acc[j]);
        }
        // two-step partial merge into part[8][16][128] (64 KB)
        float* part = smem;
        if (w < 8) {
            #pragma unroll
            for (int j = 0; j < 16; ++j)
                *(v2f*)(part + ((size_t)w * 16 + j) * 128 + lane * 2) = acc[j];
        }
        __syncthreads();
        if (w >= 8) {
            #pragma unroll
            for (int j = 0; j < 16; ++j) {
                v2f* p = (v2f*)(part + ((size_t)(w - 8) * 16 + j) * 128 + lane * 2);
                *p = *p + acc[j];
            }
        }
        __syncthreads();
        #pragma unroll
        for (int k = 0; k < 2; ++k) {
            const int id = t + k * 1024;
            const int j = id >> 7, hl = id & 127;
            const int qq = q0g + j;
            float vs = 0.f;
            #pragma unroll
            for (int gg = 0; gg < 8; ++gg) vs += part[((size_t)gg * 16 + j) * 128 + hl];
            const float D = Dp[qq] + Dp[NQ + qq];
            P2[(size_t)sh * ((size_t)NQ * HIN) + (size_t)qq * HIN + hh * 128 + hl] =
                vs * __builtin_amdgcn_rcpf(D);
        }
    }
    grid.sync();

    // ================= phase D: combine s-halves =================
    {
        const size_t idx = (size_t)blk * 1024 + t;                   // 262144 total
        out[idx] = P2[idx] + P2[(size_t)NQ * HIN + idx];
    }
}

extern "C" void kernel_launch(void* const* d_in, const int* in_sizes, int n_in,
                              void* d_out, int out_size, void* d_ws, size_t ws_size,
                              hipStream_t stream) {
    (void)in_sizes; (void)n_in; (void)out_size; (void)ws_size;
    const float* kv  = (const float*)d_in[0];
    const float* qy  = (const float*)d_in[1];
    const float* Wkv = (const float*)d_in[2];
    const float* bkv = (const float*)d_in[3];
    const float* Wq  = (const float*)d_in[4];
    const float* bq  = (const float*)d_in[5];
    const float* wv  = (const float*)d_in[6];
    // d_in[7] (b_v): constant shift — cancels in softmax

    float* ekT = (float*)d_ws;              // 262144 f
    float* eq  = ekT + 262144;              // 131072 f
    float* ew  = eq  + 131072;              // 1048576 f
    float* ewT = ew  + 1048576;             // 1048576 f
    float* Dp  = ewT + 1048576;             // 2048 f
    float* P2  = Dp  + 2048;                // 524288 f
    float* out = (float*)d_out;

    void* args[] = { (void*)&kv, (void*)&qy, (void*)&Wkv, (void*)&bkv,
                     (void*)&Wq, (void*)&bq, (void*)&wv,
                     (void*)&ekT, (void*)&eq, (void*)&ew, (void*)&ewT,
                     (void*)&Dp, (void*)&P2, (void*)&out };
    hipLaunchCooperativeKernel((const void*)fused_kernel, dim3(256), dim3(1024),
                               args, 0, stream);
}